// Round 1
// baseline (810.192 us; speedup 1.0000x reference)
//
#include <hip/hip_runtime.h>
#include <stdint.h>

#define N_NODES 8192
#define DIM 256
#define NHEADS 4
#define DHEAD 64
#define NEDGES 262144

using bf16x8 = __attribute__((ext_vector_type(8))) __bf16;
using f32x4  = __attribute__((ext_vector_type(4))) float;

__device__ __forceinline__ unsigned short f2b(float f) {
    unsigned int u = __float_as_uint(f);
    unsigned int r = (u + 0x7FFFu + ((u >> 16) & 1u)) >> 16;
    return (unsigned short)r;
}

__device__ __forceinline__ bf16x8 ld8(const unsigned short* p) {
    return *reinterpret_cast<const bf16x8*>(p);
}

// ---------------- dtype detection (int64 vs int32 edge_index) ----------------
__global__ void detect_kernel(const void* edges, int* flag) {
    if (threadIdx.x == 0) {
        const long long* p = (const long long*)edges;
        int ok = 1;
        for (int i = 0; i < 64; ++i) {
            long long v = p[i];
            if (v < 0 || v >= N_NODES) ok = 0;
        }
        *flag = ok;  // 1 => int64 storage, 0 => int32 storage
    }
}

// ---------------- clear bitmask ----------------
__global__ void clear_kernel(uint4* p, int n16) {
    int i = blockIdx.x * blockDim.x + threadIdx.x;
    if (i < n16) p[i] = make_uint4(0, 0, 0, 0);
}

// ---------------- edges -> bitmask ----------------
__global__ void edge_kernel(const void* edges, const int* flag, unsigned* mask) {
    int i = blockIdx.x * blockDim.x + threadIdx.x;
    if (i >= NEDGES) return;
    int src, dst;
    if (*flag) {
        const long long* p = (const long long*)edges;
        src = (int)p[i];
        dst = (int)p[NEDGES + i];
    } else {
        const int* p = (const int*)edges;
        src = p[i];
        dst = p[NEDGES + i];
    }
    atomicOr(&mask[src * (N_NODES / 32) + (dst >> 5)], 1u << (dst & 31));
}

// ---------------- per-row dedup mean aggregation -> bf16 ----------------
__global__ __launch_bounds__(256) void agg_kernel(const unsigned* mask, const float* x,
                                                  unsigned short* m_bf) {
    __shared__ unsigned mw[N_NODES / 32];
    int row = blockIdx.x;
    int tid = threadIdx.x;
    mw[tid] = mask[row * (N_NODES / 32) + tid];
    __syncthreads();
    int deg = 0;
    for (int w = 0; w < N_NODES / 32; ++w) deg += __popc(mw[w]);
    float acc = 0.0f;
    for (int w = 0; w < N_NODES / 32; ++w) {
        unsigned bits = mw[w];
        while (bits) {
            int b = __ffs(bits) - 1;
            bits &= bits - 1;
            acc += x[(size_t)(w * 32 + b) * DIM + tid];
        }
    }
    float s = 1.0f / (float)(deg > 0 ? deg : 1);
    m_bf[(size_t)row * DIM + tid] = f2b(acc * s);
}

// ---------------- fp32 -> bf16 weight conversion ----------------
__global__ void cvt_kernel(const float* src, unsigned short* dst, int n) {
    int i = blockIdx.x * blockDim.x + threadIdx.x;
    if (i < n) dst[i] = f2b(src[i]);
}

// ---------------- generic bf16 MFMA GEMM: C = act(A @ W^T + bias) (+res) ----
// A: M x K bf16 row-major. W: Nout x K bf16 row-major. block = 4 waves, tile 64x64.
template <int K>
__global__ __launch_bounds__(256) void gemm_kernel(const unsigned short* A,
                                                   const unsigned short* W,
                                                   const float* bias, const float* res,
                                                   float* outF, unsigned short* outB,
                                                   int Nout, int qcols, int gelu) {
    int wave = threadIdx.x >> 6, lane = threadIdx.x & 63;
    int lr = lane & 15, lq = lane >> 4;
    int r0 = blockIdx.x * 64 + wave * 16;
    int c0 = blockIdx.y * 64;
    f32x4 acc[4] = {};
    const unsigned short* arow = A + (size_t)(r0 + lr) * K + lq * 8;
#pragma unroll
    for (int kc = 0; kc < K / 32; ++kc) {
        bf16x8 af = ld8(arow + kc * 32);
#pragma unroll
        for (int ct = 0; ct < 4; ++ct) {
            bf16x8 bf = ld8(W + (size_t)(c0 + ct * 16 + lr) * K + kc * 32 + lq * 8);
            acc[ct] = __builtin_amdgcn_mfma_f32_16x16x32_bf16(af, bf, acc[ct], 0, 0, 0);
        }
    }
#pragma unroll
    for (int ct = 0; ct < 4; ++ct) {
        int col = c0 + ct * 16 + lr;
        float bi = bias[col];
#pragma unroll
        for (int r = 0; r < 4; ++r) {
            int row = r0 + lq * 4 + r;
            float g = acc[ct][r] + bi;
            if (gelu) g = 0.5f * g * (1.0f + erff(g * 0.70710678118654752f));
            if (res) g += res[(size_t)row * Nout + col];
            if (outF) outF[(size_t)row * Nout + col] = g;
            if (outB) {
                float gb = (col < qcols) ? g * 0.125f : g;
                outB[(size_t)row * Nout + col] = f2b(gb);
            }
        }
    }
}

// ---------------- flash attention (H=4, dh=64, n=8192) ----------------
// qkv: n x 768 bf16 (q pre-scaled by 1/8). out: attnb n x 256 bf16.
__global__ __launch_bounds__(256) void flash_kernel(const unsigned short* qkv,
                                                    unsigned short* attnb) {
    __shared__ unsigned short Ks[64][72];
    __shared__ unsigned short Vt[64][72];  // Vt[d][key]
    __shared__ unsigned short Ps[4][16][72];
    int h = blockIdx.y;
    int q0 = blockIdx.x * 64;
    int tid = threadIdx.x, wave = tid >> 6, lane = tid & 63;
    int lr = lane & 15, lq = lane >> 4;

    bf16x8 qf[2];
    {
        size_t base = (size_t)(q0 + wave * 16 + lr) * (3 * DIM) + h * DHEAD;
        qf[0] = ld8(qkv + base + lq * 8);
        qf[1] = ld8(qkv + base + 32 + lq * 8);
    }
    f32x4 O[4] = {};
    float m[4], l[4];
#pragma unroll
    for (int r = 0; r < 4; ++r) { m[r] = -1e30f; l[r] = 0.0f; }

    int trow = tid >> 2;           // 0..63
    int tcol = (tid & 3) * 16;     // 0,16,32,48

    for (int kt = 0; kt < N_NODES / 64; ++kt) {
        int kb = kt * 64;
        // stage K (row-major) and V (transposed)
        {
            size_t gK = (size_t)(kb + trow) * (3 * DIM) + DIM + h * DHEAD + tcol;
            uint4 k0 = *(const uint4*)(qkv + gK);
            uint4 k1 = *(const uint4*)(qkv + gK + 8);
            *(uint4*)&Ks[trow][tcol] = k0;
            *(uint4*)&Ks[trow][tcol + 8] = k1;
            const unsigned short* vp = qkv + (size_t)(kb + trow) * (3 * DIM) + 2 * DIM + h * DHEAD + tcol;
#pragma unroll
            for (int j = 0; j < 16; ++j) Vt[tcol + j][trow] = vp[j];
        }
        __syncthreads();

        // S = Q K^T  (16 q-rows per wave x 64 keys)
        f32x4 S[4];
#pragma unroll
        for (int ct = 0; ct < 4; ++ct) {
            f32x4 a = {};
#pragma unroll
            for (int kc = 0; kc < 2; ++kc) {
                bf16x8 bfr = ld8(&Ks[ct * 16 + lr][kc * 32 + lq * 8]);
                a = __builtin_amdgcn_mfma_f32_16x16x32_bf16(qf[kc], bfr, a, 0, 0, 0);
            }
            S[ct] = a;
        }

        // online softmax (rows = lq*4+r, cols across 16 lanes of the quarter)
#pragma unroll
        for (int r = 0; r < 4; ++r) {
            float mx = fmaxf(fmaxf(S[0][r], S[1][r]), fmaxf(S[2][r], S[3][r]));
            for (int d = 1; d < 16; d <<= 1) mx = fmaxf(mx, __shfl_xor(mx, d));
            float mn = fmaxf(m[r], mx);
            float sc = __expf(m[r] - mn);
            float rs = 0.0f;
#pragma unroll
            for (int ct = 0; ct < 4; ++ct) {
                float p = __expf(S[ct][r] - mn);
                S[ct][r] = p;
                rs += p;
            }
            for (int d = 1; d < 16; d <<= 1) rs += __shfl_xor(rs, d);
            l[r] = l[r] * sc + rs;
            m[r] = mn;
#pragma unroll
            for (int dt = 0; dt < 4; ++dt) O[dt][r] *= sc;
        }

        // P -> LDS (wave-private, in-order DS ops make it visible to own wave)
#pragma unroll
        for (int ct = 0; ct < 4; ++ct)
#pragma unroll
            for (int r = 0; r < 4; ++r)
                Ps[wave][lq * 4 + r][ct * 16 + lr] = f2b(S[ct][r]);

        // O += P @ V
#pragma unroll
        for (int dt = 0; dt < 4; ++dt)
#pragma unroll
            for (int kc = 0; kc < 2; ++kc) {
                bf16x8 pa = ld8(&Ps[wave][lr][kc * 32 + lq * 8]);
                bf16x8 vb = ld8(&Vt[dt * 16 + lr][kc * 32 + lq * 8]);
                O[dt] = __builtin_amdgcn_mfma_f32_16x16x32_bf16(pa, vb, O[dt], 0, 0, 0);
            }
        __syncthreads();
    }

#pragma unroll
    for (int r = 0; r < 4; ++r) {
        float inv = 1.0f / l[r];
        int row = q0 + wave * 16 + lq * 4 + r;
#pragma unroll
        for (int dt = 0; dt < 4; ++dt)
            attnb[(size_t)row * DIM + h * DHEAD + dt * 16 + lr] = f2b(O[dt][r] * inv);
    }
}

// ---------------- launch ----------------
extern "C" void kernel_launch(void* const* d_in, const int* in_sizes, int n_in,
                              void* d_out, int out_size, void* d_ws, size_t ws_size,
                              hipStream_t stream) {
    const float* x = (const float*)d_in[0];
    const void* edges = d_in[1];
    const float* W_local = (const float*)d_in[2];
    const float* b_local = (const float*)d_in[3];
    const float* W_in = (const float*)d_in[4];
    const float* b_in = (const float*)d_in[5];
    const float* W_out = (const float*)d_in[6];
    const float* b_out = (const float*)d_in[7];
    const float* W1 = (const float*)d_in[8];
    const float* b1 = (const float*)d_in[9];
    const float* W2 = (const float*)d_in[10];
    const float* b2 = (const float*)d_in[11];
    float* out = (float*)d_out;

    char* p = (char*)d_ws;
    size_t off = 0;
    auto take = [&](size_t bytes) { char* q = p + off; off += (bytes + 255) & ~(size_t)255; return q; };
    int* flag = (int*)take(256);
    unsigned* mask = (unsigned*)take((size_t)N_NODES * N_NODES / 8);
    unsigned short* m_bf = (unsigned short*)take((size_t)N_NODES * DIM * 2);
    float* x1 = (float*)take((size_t)N_NODES * DIM * 4);
    unsigned short* x1b = (unsigned short*)take((size_t)N_NODES * DIM * 2);
    unsigned short* qkvb = (unsigned short*)take((size_t)N_NODES * 3 * DIM * 2);
    unsigned short* attnb = (unsigned short*)take((size_t)N_NODES * DIM * 2);
    float* x2 = (float*)take((size_t)N_NODES * DIM * 4);
    unsigned short* x2b = (unsigned short*)take((size_t)N_NODES * DIM * 2);
    unsigned short* hb = (unsigned short*)take((size_t)N_NODES * 2 * DIM * 2);
    unsigned short* Wlb = (unsigned short*)take((size_t)DIM * DIM * 2);
    unsigned short* Winb = (unsigned short*)take((size_t)3 * DIM * DIM * 2);
    unsigned short* Wob = (unsigned short*)take((size_t)DIM * DIM * 2);
    unsigned short* W1b = (unsigned short*)take((size_t)2 * DIM * DIM * 2);
    unsigned short* W2b = (unsigned short*)take((size_t)DIM * 2 * DIM * 2);

    detect_kernel<<<1, 64, 0, stream>>>(edges, flag);
    {
        int n16 = (N_NODES * N_NODES / 8) / 16;
        clear_kernel<<<(n16 + 255) / 256, 256, 0, stream>>>((uint4*)mask, n16);
    }
    edge_kernel<<<(NEDGES + 255) / 256, 256, 0, stream>>>(edges, flag, mask);
    agg_kernel<<<N_NODES, 256, 0, stream>>>(mask, x, m_bf);

    cvt_kernel<<<(DIM * DIM + 255) / 256, 256, 0, stream>>>(W_local, Wlb, DIM * DIM);
    cvt_kernel<<<(3 * DIM * DIM + 255) / 256, 256, 0, stream>>>(W_in, Winb, 3 * DIM * DIM);
    cvt_kernel<<<(DIM * DIM + 255) / 256, 256, 0, stream>>>(W_out, Wob, DIM * DIM);
    cvt_kernel<<<(2 * DIM * DIM + 255) / 256, 256, 0, stream>>>(W1, W1b, 2 * DIM * DIM);
    cvt_kernel<<<(2 * DIM * DIM + 255) / 256, 256, 0, stream>>>(W2, W2b, 2 * DIM * DIM);

    // x1 = x + (m @ W_local^T + b_local)
    gemm_kernel<DIM><<<dim3(N_NODES / 64, DIM / 64), 256, 0, stream>>>(
        m_bf, Wlb, b_local, x, x1, x1b, DIM, 0, 0);
    // qkv = x1 @ W_in^T + b_in  (q cols scaled by 1/8 in bf16 copy)
    gemm_kernel<DIM><<<dim3(N_NODES / 64, 3 * DIM / 64), 256, 0, stream>>>(
        x1b, Winb, b_in, nullptr, nullptr, qkvb, 3 * DIM, DIM, 0);
    // flash attention
    flash_kernel<<<dim3(N_NODES / 64, NHEADS), 256, 0, stream>>>(qkvb, attnb);
    // x2 = x1 + (attn @ W_out^T + b_out)
    gemm_kernel<DIM><<<dim3(N_NODES / 64, DIM / 64), 256, 0, stream>>>(
        attnb, Wob, b_out, x1, x2, x2b, DIM, 0, 0);
    // h = gelu(x2 @ W1^T + b1)
    gemm_kernel<DIM><<<dim3(N_NODES / 64, 2 * DIM / 64), 256, 0, stream>>>(
        x2b, W1b, b1, nullptr, nullptr, hb, 2 * DIM, 0, 1);
    // out = x2 + (h @ W2^T + b2)
    gemm_kernel<2 * DIM><<<dim3(N_NODES / 64, DIM / 64), 256, 0, stream>>>(
        hb, W2b, b2, x2, out, nullptr, DIM, 0, 0);
}

// Round 2
// 488.019 us; speedup vs baseline: 1.6602x; 1.6602x over previous
//
#include <hip/hip_runtime.h>
#include <stdint.h>

#define N_NODES 8192
#define DIM 256
#define NHEADS 4
#define DHEAD 64
#define NEDGES 262144

using bf16x8 = __attribute__((ext_vector_type(8))) __bf16;
using f32x4  = __attribute__((ext_vector_type(4))) float;

__device__ __forceinline__ unsigned short f2b(float f) {
    unsigned int u = __float_as_uint(f);
    unsigned int r = (u + 0x7FFFu + ((u >> 16) & 1u)) >> 16;
    return (unsigned short)r;
}

__device__ __forceinline__ bf16x8 ld8(const unsigned short* p) {
    return *reinterpret_cast<const bf16x8*>(p);
}

// ---------------- dtype detection (int64 vs int32 edge_index) ----------------
__global__ void detect_kernel(const void* edges, int* flag) {
    if (threadIdx.x == 0) {
        const long long* p = (const long long*)edges;
        int ok = 1;
        for (int i = 0; i < 64; ++i) {
            long long v = p[i];
            if (v < 0 || v >= N_NODES) ok = 0;
        }
        *flag = ok;  // 1 => int64 storage, 0 => int32 storage
    }
}

// ---------------- clear bitmask ----------------
__global__ void clear_kernel(uint4* p, int n16) {
    int i = blockIdx.x * blockDim.x + threadIdx.x;
    if (i < n16) p[i] = make_uint4(0, 0, 0, 0);
}

// ---------------- edges -> bitmask ----------------
__global__ void edge_kernel(const void* edges, const int* flag, unsigned* mask) {
    int i = blockIdx.x * blockDim.x + threadIdx.x;
    if (i >= NEDGES) return;
    int src, dst;
    if (*flag) {
        const long long* p = (const long long*)edges;
        src = (int)p[i];
        dst = (int)p[NEDGES + i];
    } else {
        const int* p = (const int*)edges;
        src = p[i];
        dst = p[NEDGES + i];
    }
    atomicOr(&mask[src * (N_NODES / 32) + (dst >> 5)], 1u << (dst & 31));
}

// ---------------- per-row dedup mean aggregation -> bf16 ----------------
// One block per row. Thread t owns mask word t; block-wide prefix sum
// compacts neighbor ids into LDS (deterministic sorted order), then a
// deg-iteration coalesced gather accumulates.
__global__ __launch_bounds__(256) void agg_kernel(const unsigned* mask, const float* x,
                                                  unsigned short* m_bf) {
    __shared__ int nbr[N_NODES];
    __shared__ int wsum[4];
    int row = blockIdx.x;
    int tid = threadIdx.x, wave = tid >> 6, lane = tid & 63;

    unsigned bits = mask[row * (N_NODES / 32) + tid];
    int cnt = __popc(bits);
    // inclusive scan of cnt within wave
    int scan = cnt;
#pragma unroll
    for (int d = 1; d < 64; d <<= 1) {
        int v = __shfl_up(scan, d);
        if (lane >= d) scan += v;
    }
    if (lane == 63) wsum[wave] = scan;
    __syncthreads();
    int base = 0;
    for (int w = 0; w < 4; ++w) {
        int t = wsum[w];
        if (w < wave) base += t;
    }
    int deg = wsum[0] + wsum[1] + wsum[2] + wsum[3];
    int offset = base + scan - cnt;  // exclusive prefix
    int nb = tid * 32;
    unsigned b2 = bits;
    while (b2) {
        int b = __ffs(b2) - 1;
        b2 &= b2 - 1;
        nbr[offset++] = nb + b;
    }
    __syncthreads();

    float a0 = 0.f, a1 = 0.f, a2 = 0.f, a3 = 0.f;
    int j = 0;
    for (; j + 4 <= deg; j += 4) {
        int n0 = nbr[j], n1 = nbr[j + 1], n2 = nbr[j + 2], n3 = nbr[j + 3];
        a0 += x[(size_t)n0 * DIM + tid];
        a1 += x[(size_t)n1 * DIM + tid];
        a2 += x[(size_t)n2 * DIM + tid];
        a3 += x[(size_t)n3 * DIM + tid];
    }
    for (; j < deg; ++j) a0 += x[(size_t)nbr[j] * DIM + tid];
    float acc = (a0 + a1) + (a2 + a3);
    float s = 1.0f / (float)(deg > 0 ? deg : 1);
    m_bf[(size_t)row * DIM + tid] = f2b(acc * s);
}

// ---------------- fp32 -> bf16 weight conversion ----------------
__global__ void cvt_kernel(const float* src, unsigned short* dst, int n) {
    int i = blockIdx.x * blockDim.x + threadIdx.x;
    if (i < n) dst[i] = f2b(src[i]);
}

// ---------------- generic bf16 MFMA GEMM: C = act(A @ W^T + bias) (+res) ----
// A: M x K bf16 row-major. W: Nout x K bf16 row-major. block = 4 waves, tile 64x64.
template <int K>
__global__ __launch_bounds__(256) void gemm_kernel(const unsigned short* A,
                                                   const unsigned short* W,
                                                   const float* bias, const float* res,
                                                   float* outF, unsigned short* outB,
                                                   int Nout, int qcols, int gelu) {
    int wave = threadIdx.x >> 6, lane = threadIdx.x & 63;
    int lr = lane & 15, lq = lane >> 4;
    int r0 = blockIdx.x * 64 + wave * 16;
    int c0 = blockIdx.y * 64;
    f32x4 acc[4] = {};
    const unsigned short* arow = A + (size_t)(r0 + lr) * K + lq * 8;
#pragma unroll
    for (int kc = 0; kc < K / 32; ++kc) {
        bf16x8 af = ld8(arow + kc * 32);
#pragma unroll
        for (int ct = 0; ct < 4; ++ct) {
            bf16x8 bf = ld8(W + (size_t)(c0 + ct * 16 + lr) * K + kc * 32 + lq * 8);
            acc[ct] = __builtin_amdgcn_mfma_f32_16x16x32_bf16(af, bf, acc[ct], 0, 0, 0);
        }
    }
#pragma unroll
    for (int ct = 0; ct < 4; ++ct) {
        int col = c0 + ct * 16 + lr;
        float bi = bias[col];
#pragma unroll
        for (int r = 0; r < 4; ++r) {
            int row = r0 + lq * 4 + r;
            float g = acc[ct][r] + bi;
            if (gelu) g = 0.5f * g * (1.0f + erff(g * 0.70710678118654752f));
            if (res) g += res[(size_t)row * Nout + col];
            if (outF) outF[(size_t)row * Nout + col] = g;
            if (outB) {
                float gb = (col < qcols) ? g * 0.125f : g;
                outB[(size_t)row * Nout + col] = f2b(gb);
            }
        }
    }
}

// ---------------- flash attention (H=4, dh=64, n=8192) ----------------
// qkv: n x 768 bf16 (q pre-scaled by 1/8). out: attnb n x 256 bf16.
__global__ __launch_bounds__(256) void flash_kernel(const unsigned short* qkv,
                                                    unsigned short* attnb) {
    __shared__ unsigned short Ks[64][72];
    __shared__ unsigned short Vt[64][72];  // Vt[d][key]
    __shared__ unsigned short Ps[4][16][72];
    int h = blockIdx.y;
    int q0 = blockIdx.x * 64;
    int tid = threadIdx.x, wave = tid >> 6, lane = tid & 63;
    int lr = lane & 15, lq = lane >> 4;

    bf16x8 qf[2];
    {
        size_t base = (size_t)(q0 + wave * 16 + lr) * (3 * DIM) + h * DHEAD;
        qf[0] = ld8(qkv + base + lq * 8);
        qf[1] = ld8(qkv + base + 32 + lq * 8);
    }
    f32x4 O[4] = {};
    float m[4], l[4];
#pragma unroll
    for (int r = 0; r < 4; ++r) { m[r] = -1e30f; l[r] = 0.0f; }

    int trow = tid >> 2;           // 0..63
    int tcol = (tid & 3) * 16;     // 0,16,32,48

    for (int kt = 0; kt < N_NODES / 64; ++kt) {
        int kb = kt * 64;
        // stage K (row-major) and V (transposed)
        {
            size_t gK = (size_t)(kb + trow) * (3 * DIM) + DIM + h * DHEAD + tcol;
            uint4 k0 = *(const uint4*)(qkv + gK);
            uint4 k1 = *(const uint4*)(qkv + gK + 8);
            *(uint4*)&Ks[trow][tcol] = k0;
            *(uint4*)&Ks[trow][tcol + 8] = k1;
            const unsigned short* vp = qkv + (size_t)(kb + trow) * (3 * DIM) + 2 * DIM + h * DHEAD + tcol;
#pragma unroll
            for (int j = 0; j < 16; ++j) Vt[tcol + j][trow] = vp[j];
        }
        __syncthreads();

        // S = Q K^T  (16 q-rows per wave x 64 keys)
        f32x4 S[4];
#pragma unroll
        for (int ct = 0; ct < 4; ++ct) {
            f32x4 a = {};
#pragma unroll
            for (int kc = 0; kc < 2; ++kc) {
                bf16x8 bfr = ld8(&Ks[ct * 16 + lr][kc * 32 + lq * 8]);
                a = __builtin_amdgcn_mfma_f32_16x16x32_bf16(qf[kc], bfr, a, 0, 0, 0);
            }
            S[ct] = a;
        }

        // online softmax (rows = lq*4+r, cols across 16 lanes of the quarter)
#pragma unroll
        for (int r = 0; r < 4; ++r) {
            float mx = fmaxf(fmaxf(S[0][r], S[1][r]), fmaxf(S[2][r], S[3][r]));
            for (int d = 1; d < 16; d <<= 1) mx = fmaxf(mx, __shfl_xor(mx, d));
            float mn = fmaxf(m[r], mx);
            float sc = __expf(m[r] - mn);
            float rs = 0.0f;
#pragma unroll
            for (int ct = 0; ct < 4; ++ct) {
                float p = __expf(S[ct][r] - mn);
                S[ct][r] = p;
                rs += p;
            }
            for (int d = 1; d < 16; d <<= 1) rs += __shfl_xor(rs, d);
            l[r] = l[r] * sc + rs;
            m[r] = mn;
#pragma unroll
            for (int dt = 0; dt < 4; ++dt) O[dt][r] *= sc;
        }

        // P -> LDS (wave-private, in-order DS ops make it visible to own wave)
#pragma unroll
        for (int ct = 0; ct < 4; ++ct)
#pragma unroll
            for (int r = 0; r < 4; ++r)
                Ps[wave][lq * 4 + r][ct * 16 + lr] = f2b(S[ct][r]);

        // O += P @ V
#pragma unroll
        for (int dt = 0; dt < 4; ++dt)
#pragma unroll
            for (int kc = 0; kc < 2; ++kc) {
                bf16x8 pa = ld8(&Ps[wave][lr][kc * 32 + lq * 8]);
                bf16x8 vb = ld8(&Vt[dt * 16 + lr][kc * 32 + lq * 8]);
                O[dt] = __builtin_amdgcn_mfma_f32_16x16x32_bf16(pa, vb, O[dt], 0, 0, 0);
            }
        __syncthreads();
    }

#pragma unroll
    for (int r = 0; r < 4; ++r) {
        float inv = 1.0f / l[r];
        int row = q0 + wave * 16 + lq * 4 + r;
#pragma unroll
        for (int dt = 0; dt < 4; ++dt)
            attnb[(size_t)row * DIM + h * DHEAD + dt * 16 + lr] = f2b(O[dt][r] * inv);
    }
}

// ---------------- launch ----------------
extern "C" void kernel_launch(void* const* d_in, const int* in_sizes, int n_in,
                              void* d_out, int out_size, void* d_ws, size_t ws_size,
                              hipStream_t stream) {
    const float* x = (const float*)d_in[0];
    const void* edges = d_in[1];
    const float* W_local = (const float*)d_in[2];
    const float* b_local = (const float*)d_in[3];
    const float* W_in = (const float*)d_in[4];
    const float* b_in = (const float*)d_in[5];
    const float* W_out = (const float*)d_in[6];
    const float* b_out = (const float*)d_in[7];
    const float* W1 = (const float*)d_in[8];
    const float* b1 = (const float*)d_in[9];
    const float* W2 = (const float*)d_in[10];
    const float* b2 = (const float*)d_in[11];
    float* out = (float*)d_out;

    char* p = (char*)d_ws;
    size_t off = 0;
    auto take = [&](size_t bytes) { char* q = p + off; off += (bytes + 255) & ~(size_t)255; return q; };
    int* flag = (int*)take(256);
    unsigned* mask = (unsigned*)take((size_t)N_NODES * N_NODES / 8);
    unsigned short* m_bf = (unsigned short*)take((size_t)N_NODES * DIM * 2);
    float* x1 = (float*)take((size_t)N_NODES * DIM * 4);
    unsigned short* x1b = (unsigned short*)take((size_t)N_NODES * DIM * 2);
    unsigned short* qkvb = (unsigned short*)take((size_t)N_NODES * 3 * DIM * 2);
    unsigned short* attnb = (unsigned short*)take((size_t)N_NODES * DIM * 2);
    float* x2 = (float*)take((size_t)N_NODES * DIM * 4);
    unsigned short* x2b = (unsigned short*)take((size_t)N_NODES * DIM * 2);
    unsigned short* hb = (unsigned short*)take((size_t)N_NODES * 2 * DIM * 2);
    unsigned short* Wlb = (unsigned short*)take((size_t)DIM * DIM * 2);
    unsigned short* Winb = (unsigned short*)take((size_t)3 * DIM * DIM * 2);
    unsigned short* Wob = (unsigned short*)take((size_t)DIM * DIM * 2);
    unsigned short* W1b = (unsigned short*)take((size_t)2 * DIM * DIM * 2);
    unsigned short* W2b = (unsigned short*)take((size_t)DIM * 2 * DIM * 2);

    detect_kernel<<<1, 64, 0, stream>>>(edges, flag);
    {
        int n16 = (N_NODES * N_NODES / 8) / 16;
        clear_kernel<<<(n16 + 255) / 256, 256, 0, stream>>>((uint4*)mask, n16);
    }
    edge_kernel<<<(NEDGES + 255) / 256, 256, 0, stream>>>(edges, flag, mask);
    agg_kernel<<<N_NODES, 256, 0, stream>>>(mask, x, m_bf);

    cvt_kernel<<<(DIM * DIM + 255) / 256, 256, 0, stream>>>(W_local, Wlb, DIM * DIM);
    cvt_kernel<<<(3 * DIM * DIM + 255) / 256, 256, 0, stream>>>(W_in, Winb, 3 * DIM * DIM);
    cvt_kernel<<<(DIM * DIM + 255) / 256, 256, 0, stream>>>(W_out, Wob, DIM * DIM);
    cvt_kernel<<<(2 * DIM * DIM + 255) / 256, 256, 0, stream>>>(W1, W1b, 2 * DIM * DIM);
    cvt_kernel<<<(2 * DIM * DIM + 255) / 256, 256, 0, stream>>>(W2, W2b, 2 * DIM * DIM);

    // x1 = x + (m @ W_local^T + b_local)
    gemm_kernel<DIM><<<dim3(N_NODES / 64, DIM / 64), 256, 0, stream>>>(
        m_bf, Wlb, b_local, x, x1, x1b, DIM, 0, 0);
    // qkv = x1 @ W_in^T + b_in  (q cols scaled by 1/8 in bf16 copy)
    gemm_kernel<DIM><<<dim3(N_NODES / 64, 3 * DIM / 64), 256, 0, stream>>>(
        x1b, Winb, b_in, nullptr, nullptr, qkvb, 3 * DIM, DIM, 0);
    // flash attention
    flash_kernel<<<dim3(N_NODES / 64, NHEADS), 256, 0, stream>>>(qkvb, attnb);
    // x2 = x1 + (attn @ W_out^T + b_out)
    gemm_kernel<DIM><<<dim3(N_NODES / 64, DIM / 64), 256, 0, stream>>>(
        attnb, Wob, b_out, x1, x2, x2b, DIM, 0, 0);
    // h = gelu(x2 @ W1^T + b1)
    gemm_kernel<DIM><<<dim3(N_NODES / 64, 2 * DIM / 64), 256, 0, stream>>>(
        x2b, W1b, b1, nullptr, nullptr, hb, 2 * DIM, 0, 1);
    // out = x2 + (h @ W2^T + b2)
    gemm_kernel<2 * DIM><<<dim3(N_NODES / 64, DIM / 64), 256, 0, stream>>>(
        hb, W2b, b2, x2, out, nullptr, DIM, 0, 0);
}